// Round 4
// baseline (120.676 us; speedup 1.0000x reference)
//
#include <hip/hip_runtime.h>

#define KK 8
#define CC 16

typedef int   vint4   __attribute__((ext_vector_type(4)));
typedef float vfloat4 __attribute__((ext_vector_type(4)));
typedef unsigned int vuint2 __attribute__((ext_vector_type(2)));

static __device__ __forceinline__ unsigned short f32_to_bf16(float x) {
    unsigned int b = __float_as_uint(x);
    unsigned int r = b + 0x7FFFu + ((b >> 16) & 1u);
    return (unsigned short)(r >> 16);
}
static __device__ __forceinline__ float bf16_to_f32(unsigned short u) {
    return __uint_as_float(((unsigned int)u) << 16);
}

// Prep: features (C,P) f32 -> (P,C) bf16 packed records (32B/point), and
// inv_r2[p] = 1/r^2 (f32). Both live in d_ws.
__global__ void prep_kernel(const float* __restrict__ f,
                            const float* __restrict__ radii,
                            unsigned short* __restrict__ ft,
                            float* __restrict__ inv_r2, int P) {
    int p = blockIdx.x * blockDim.x + threadIdx.x;
    if (p >= P) return;
    float r = radii[p];
    inv_r2[p] = 1.0f / (r * r);
    unsigned int w[8];
#pragma unroll
    for (int j = 0; j < 8; ++j) {
        unsigned int lo = f32_to_bf16(f[(size_t)(2 * j) * P + p]);
        unsigned int hi = f32_to_bf16(f[(size_t)(2 * j + 1) * P + p]);
        w[j] = lo | (hi << 16);
    }
    uint4* dst = (uint4*)(ft + (size_t)p * CC);
    dst[0] = make_uint4(w[0], w[1], w[2], w[3]);
    dst[1] = make_uint4(w[4], w[5], w[6], w[7]);
}

// 4 lanes per pixel; lane q owns channels [4q, 4q+4). Branchless: all 16
// gather loads (8 inv_r2 + 8 feature chunks) are unconditional and
// address-independent -> issued together, latency amortized over one wait.
// Invalid slots (idx == -1) read record 0 (stays hot in L2) with weight 0.
__global__ void render_kernel(const int* __restrict__ idx,
                              const float* __restrict__ dists,
                              const float* __restrict__ inv_r2,
                              const unsigned short* __restrict__ ft,
                              float* __restrict__ out, int npix) {
    int tid = blockIdx.x * blockDim.x + threadIdx.x;
    int pix = tid >> 2;
    int q = tid & 3;
    if (pix >= npix) return;

    // Streaming reads: non-temporal (read-once; don't evict the gather table)
    const vint4* ip = (const vint4*)(idx + (size_t)pix * KK);
    const vfloat4* dp = (const vfloat4*)(dists + (size_t)pix * KK);
    vint4 i0 = __builtin_nontemporal_load(ip);
    vint4 i1 = __builtin_nontemporal_load(ip + 1);
    vfloat4 dv0 = __builtin_nontemporal_load(dp);
    vfloat4 dv1 = __builtin_nontemporal_load(dp + 1);
    int ids[KK] = {i0.x, i0.y, i0.z, i0.w, i1.x, i1.y, i1.z, i1.w};
    float ds[KK] = {dv0.x, dv0.y, dv0.z, dv0.w, dv1.x, dv1.y, dv1.z, dv1.w};

    float ir2[KK];
    vuint2 pk[KK];
    float vld[KK];
#pragma unroll
    for (int k = 0; k < KK; ++k) {
        int id = ids[k];
        int sid = id < 0 ? 0 : id;  // v_max_i32
        vld[k] = id < 0 ? 0.0f : 1.0f;
        ir2[k] = inv_r2[sid];
        pk[k] = *(const vuint2*)(ft + (size_t)sid * CC + q * 4);
    }

    float a0 = 0.f, a1 = 0.f, a2 = 0.f, a3 = 0.f;
    float T = 1.0f;
#pragma unroll
    for (int k = 0; k < KK; ++k) {
        float w = (1.0f - ds[k] * ir2[k]) * vld[k];
        float a = w * T;
        T *= (1.0f - w);
        a0 += a * bf16_to_f32((unsigned short)(pk[k].x & 0xFFFFu));
        a1 += a * bf16_to_f32((unsigned short)(pk[k].x >> 16));
        a2 += a * bf16_to_f32((unsigned short)(pk[k].y & 0xFFFFu));
        a3 += a * bf16_to_f32((unsigned short)(pk[k].y >> 16));
    }

    // Streaming write: non-temporal
    vfloat4* op = (vfloat4*)(out + (size_t)pix * CC + q * 4);
    vfloat4 res = {a0, a1, a2, a3};
    __builtin_nontemporal_store(res, op);
}

extern "C" void kernel_launch(void* const* d_in, const int* in_sizes, int n_in,
                              void* d_out, int out_size, void* d_ws, size_t ws_size,
                              hipStream_t stream) {
    const int* idx = (const int*)d_in[0];
    const float* dists = (const float*)d_in[1];
    const float* radii = (const float*)d_in[2];
    const float* features = (const float*)d_in[3];
    float* out = (float*)d_out;

    int P = in_sizes[2];          // 200000
    int npix = in_sizes[0] / KK;  // B*H*W = 1048576

    unsigned short* ft = (unsigned short*)d_ws;                 // P*32B = 6.4MB
    float* inv_r2 = (float*)((char*)d_ws + (size_t)P * CC * 2); // +800KB

    prep_kernel<<<(P + 255) / 256, 256, 0, stream>>>(features, radii, ft, inv_r2, P);

    int nthreads = npix * 4;
    render_kernel<<<(nthreads + 255) / 256, 256, 0, stream>>>(
        idx, dists, inv_r2, ft, out, npix);
}